// Round 2
// baseline (7128.737 us; speedup 1.0000x reference)
//
#include <hip/hip_runtime.h>

#define NN 100000
#define NE 1600000
#define NB 64
#define DIN 78
#define DH 128
#define SD 768
#define FD 256

// 1/sqrt(1 + 1e-5)
#define BN_SCALE 0.9999950000374997f

// ---------------- elementwise copy (float2) ----------------
__global__ void copy2_kernel(const float2* __restrict__ s, float2* __restrict__ d, int n2) {
    int i = blockIdx.x * blockDim.x + threadIdx.x;
    if (i < n2) d[i] = s[i];
}

// ---------------- edge aggregation: z[dst] += h[src] ----------------
// D=78, float2 chunks (39 per edge)
__global__ void edge_agg78(const float* __restrict__ h, const int* __restrict__ src,
                           const int* __restrict__ dst, float* __restrict__ z) {
    unsigned tid = blockIdx.x * 256u + threadIdx.x;
    unsigned e = tid / 39u;
    if (e >= NE) return;
    unsigned c = (tid - e * 39u) * 2u;
    int s = src[e], d = dst[e];
    float2 v = *(const float2*)&h[(size_t)s * DIN + c];
    float* zp = &z[(size_t)d * DIN + c];
    unsafeAtomicAdd(zp + 0, v.x);
    unsafeAtomicAdd(zp + 1, v.y);
}

// D=128, float4 chunks (32 per edge)
__global__ void edge_agg128(const float* __restrict__ h, const int* __restrict__ src,
                            const int* __restrict__ dst, float* __restrict__ z) {
    unsigned tid = blockIdx.x * 256u + threadIdx.x;
    unsigned e = tid >> 5;
    if (e >= NE) return;
    unsigned c = (tid & 31u) << 2;
    int s = src[e], d = dst[e];
    float4 v = *(const float4*)&h[(size_t)s * DH + c];
    float* zp = &z[(size_t)d * DH + c];
    unsafeAtomicAdd(zp + 0, v.x);
    unsafeAtomicAdd(zp + 1, v.y);
    unsafeAtomicAdd(zp + 2, v.z);
    unsafeAtomicAdd(zp + 3, v.w);
}

// ---------------- GEMM: C[N,128] = epi(A[N,K] @ W[K,128]) ----------------
// EPI 0: relu(acc + bias)
// EPI 1: relu((acc + bias) * (g*BN_SCALE) + bb)
template <int K, int EPI>
__global__ __launch_bounds__(256) void gemm_epi(
        const float* __restrict__ A, const float* __restrict__ W,
        const float* __restrict__ bias, const float* __restrict__ g,
        const float* __restrict__ bb, float* __restrict__ C, int nrows) {
    constexpr int BM = 64, BN = 128, BK = 64;
    __shared__ float As[BK][BM];   // transposed: As[k][row]
    __shared__ float Bs[BK][BN];
    const int tid = threadIdx.x;
    const int tx = tid & 15;       // col group (8 cols)
    const int ty = tid >> 4;       // row group (4 rows)
    const int r0 = blockIdx.x * BM;

    float acc[4][8];
#pragma unroll
    for (int i = 0; i < 4; ++i)
#pragma unroll
        for (int j = 0; j < 8; ++j) acc[i][j] = 0.f;

    const int tr = tid >> 2;       // 0..63 : A row within tile
    const int l4 = tid & 3;
    const int arow = r0 + tr;
    const bool aok = arow < nrows;

    for (int kt = 0; kt < K; kt += BK) {
        const int ksz = (K - kt < BK) ? (K - kt) : BK;
        // B tile: rows kt..kt+ksz-1 of W, full 128 wide, float4 loads
        for (int i = tid; i < ksz * (BN / 4); i += 256) {
            int kk = i >> 5;
            int cc = (i & 31) << 2;
            *(float4*)&Bs[kk][cc] = *(const float4*)&W[(size_t)(kt + kk) * BN + cc];
        }
        // A tile transposed
        for (int k = l4; k < ksz; k += 4)
            As[k][tr] = aok ? A[(size_t)arow * K + kt + k] : 0.f;
        __syncthreads();

        if (ksz == BK) {
#pragma unroll
            for (int k = 0; k < BK; ++k) {
                float4 a4 = *(const float4*)&As[k][ty * 4];
                float4 b0 = *(const float4*)&Bs[k][tx * 8];
                float4 b1 = *(const float4*)&Bs[k][tx * 8 + 4];
                float av[4] = {a4.x, a4.y, a4.z, a4.w};
                float bv[8] = {b0.x, b0.y, b0.z, b0.w, b1.x, b1.y, b1.z, b1.w};
#pragma unroll
                for (int i = 0; i < 4; ++i)
#pragma unroll
                    for (int j = 0; j < 8; ++j)
                        acc[i][j] = fmaf(av[i], bv[j], acc[i][j]);
            }
        } else {
            for (int k = 0; k < ksz; ++k) {
                float4 a4 = *(const float4*)&As[k][ty * 4];
                float4 b0 = *(const float4*)&Bs[k][tx * 8];
                float4 b1 = *(const float4*)&Bs[k][tx * 8 + 4];
                float av[4] = {a4.x, a4.y, a4.z, a4.w};
                float bv[8] = {b0.x, b0.y, b0.z, b0.w, b1.x, b1.y, b1.z, b1.w};
#pragma unroll
                for (int i = 0; i < 4; ++i)
#pragma unroll
                    for (int j = 0; j < 8; ++j)
                        acc[i][j] = fmaf(av[i], bv[j], acc[i][j]);
            }
        }
        __syncthreads();
    }

    // epilogue
#pragma unroll
    for (int i = 0; i < 4; ++i) {
        int row = r0 + ty * 4 + i;
        if (row >= nrows) continue;
        float out[8];
#pragma unroll
        for (int j = 0; j < 8; ++j) {
            int col = tx * 8 + j;
            float v = acc[i][j] + bias[col];
            if constexpr (EPI == 1) {
                v = v * (g[col] * BN_SCALE) + bb[col];
            }
            out[j] = fmaxf(v, 0.f);
        }
        *(float4*)&C[(size_t)row * BN + tx * 8] = *(float4*)&out[0];
        *(float4*)&C[(size_t)row * BN + tx * 8 + 4] = *(float4*)&out[4];
    }
}

// ---------------- global mean pool ----------------
// 64 blocks (one per graph) x 1024 threads: tid = chunk*128 + f.
// Each of the 8 chunks strides the graph's node rows; LDS tree-reduce.
__device__ __forceinline__ int lower_bound_i(const int* a, int n, int v) {
    int lo = 0, hi = n;
    while (lo < hi) {
        int m = (lo + hi) >> 1;
        if (a[m] < v) lo = m + 1; else hi = m;
    }
    return lo;
}

__global__ __launch_bounds__(1024) void pool_kernel(const float* __restrict__ h,
                                                    const int* __restrict__ batch,
                                                    float* __restrict__ gf) {
    int b = blockIdx.x;
    int f = threadIdx.x & 127;
    int chunk = threadIdx.x >> 7;   // 0..7
    __shared__ float part[8][DH];
    int lo = lower_bound_i(batch, NN, b);
    int hi = lower_bound_i(batch, NN, b + 1);
    float sum = 0.f;
    for (int i = lo + chunk; i < hi; i += 8) sum += h[(size_t)i * DH + f];
    part[chunk][f] = sum;
    __syncthreads();
    if (chunk == 0) {
        float s = part[0][f] + part[1][f] + part[2][f] + part[3][f] +
                  part[4][f] + part[5][f] + part[6][f] + part[7][f];
        int cnt = hi - lo;
        gf[b * DH + f] = s / (float)(cnt > 0 ? cnt : 1);
    }
}

// ---------------- fusion + attention + classifier ----------------
__global__ __launch_bounds__(256) void fusion_kernel(
        const float* __restrict__ sem, const float* __restrict__ gf,
        const float* __restrict__ Ws, const float* __restrict__ bs,
        const float* __restrict__ Wg, const float* __restrict__ bg,
        const float* __restrict__ Wq, const float* __restrict__ Wk,
        const float* __restrict__ Wv,
        const float* __restrict__ Wc1, const float* __restrict__ bc1,
        const float* __restrict__ Wc2, const float* __restrict__ bc2,
        float* __restrict__ out) {
    int b = blockIdx.x;
    int c = threadIdx.x;  // 256
    __shared__ float tok[2][FD];
    __shared__ float qv[6][FD];   // q0 q1 k0 k1 v0 v1
    __shared__ float att[4];
    __shared__ float fused[FD];
    __shared__ float c1[FD / 2];

    // token 0: semantic projection (K=768)
    {
        float acc = bs[c];
        const float* sr = &sem[(size_t)b * SD];
#pragma unroll 8
        for (int k = 0; k < SD; ++k) acc = fmaf(sr[k], Ws[(size_t)k * FD + c], acc);
        tok[0][c] = acc;
    }
    // token 1: graph projection (K=128)
    {
        float acc = bg[c];
        const float* gr = &gf[(size_t)b * DH];
#pragma unroll 8
        for (int k = 0; k < DH; ++k) acc = fmaf(gr[k], Wg[(size_t)k * FD + c], acc);
        tok[1][c] = acc;
    }
    __syncthreads();

    // q,k,v for both tokens
#pragma unroll
    for (int t = 0; t < 2; ++t) {
        float qa = 0.f, ka = 0.f, va = 0.f;
#pragma unroll 4
        for (int k = 0; k < FD; ++k) {
            float tv = tok[t][k];
            qa = fmaf(tv, Wq[(size_t)k * FD + c], qa);
            ka = fmaf(tv, Wk[(size_t)k * FD + c], ka);
            va = fmaf(tv, Wv[(size_t)k * FD + c], va);
        }
        qv[0 + t][c] = qa;
        qv[2 + t][c] = ka;
        qv[4 + t][c] = va;
    }
    __syncthreads();

    // scores + softmax (sqrt(FD)=16)
    if (c < 4) {
        int qi = c >> 1, ki = c & 1;
        float s = 0.f;
        for (int k = 0; k < FD; ++k) s += qv[qi][k] * qv[2 + ki][k];
        att[c] = s * (1.0f / 16.0f);
    }
    __syncthreads();
    if (c < 2) {
        float a0 = att[c * 2], a1 = att[c * 2 + 1];
        float m = fmaxf(a0, a1);
        float e0 = __expf(a0 - m), e1 = __expf(a1 - m);
        float inv = 1.f / (e0 + e1);
        att[c * 2] = e0 * inv;
        att[c * 2 + 1] = e1 * inv;
    }
    __syncthreads();

    // fused = mean over q of att@v
    fused[c] = 0.5f * (att[0] * qv[4][c] + att[1] * qv[5][c] +
                       att[2] * qv[4][c] + att[3] * qv[5][c]);
    __syncthreads();

    // classifier layer 1 (256 -> 128)
    if (c < FD / 2) {
        float acc = bc1[c];
#pragma unroll 4
        for (int k = 0; k < FD; ++k) acc = fmaf(fused[k], Wc1[(size_t)k * (FD / 2) + c], acc);
        c1[c] = fmaxf(acc, 0.f);
    }
    __syncthreads();

    // classifier layer 2 (128 -> 2)
    if (c < 2) {
        float acc = bc2[c];
        for (int k = 0; k < FD / 2; ++k) acc = fmaf(c1[k], Wc2[(size_t)k * 2 + c], acc);
        out[b * 2 + c] = acc;
    }
}

// ---------------- launch ----------------
extern "C" void kernel_launch(void* const* d_in, const int* in_sizes, int n_in,
                              void* d_out, int out_size, void* d_ws, size_t ws_size,
                              hipStream_t stream) {
    const float* sem   = (const float*)d_in[0];
    const float* x     = (const float*)d_in[1];
    const int*   ei    = (const int*)d_in[2];
    const int*   batch = (const int*)d_in[3];
    const int* src = ei;
    const int* dst = ei + NE;

    const float* c1W1 = (const float*)d_in[4];
    const float* c1b1 = (const float*)d_in[5];
    const float* c1W2 = (const float*)d_in[6];
    const float* c1b2 = (const float*)d_in[7];
    const float* c2W1 = (const float*)d_in[8];
    const float* c2b1 = (const float*)d_in[9];
    const float* c2W2 = (const float*)d_in[10];
    const float* c2b2 = (const float*)d_in[11];
    const float* c3W1 = (const float*)d_in[12];
    const float* c3b1 = (const float*)d_in[13];
    const float* c3W2 = (const float*)d_in[14];
    const float* c3b2 = (const float*)d_in[15];
    const float* bn1g = (const float*)d_in[16];
    const float* bn1b = (const float*)d_in[17];
    const float* bn2g = (const float*)d_in[18];
    const float* bn2b = (const float*)d_in[19];
    const float* bn3g = (const float*)d_in[20];
    const float* bn3b = (const float*)d_in[21];
    const float* Ws   = (const float*)d_in[22];
    const float* bs_  = (const float*)d_in[23];
    const float* Wg   = (const float*)d_in[24];
    const float* bg   = (const float*)d_in[25];
    const float* Wq   = (const float*)d_in[26];
    const float* Wk   = (const float*)d_in[27];
    const float* Wv   = (const float*)d_in[28];
    const float* Wc1  = (const float*)d_in[29];
    const float* bc1  = (const float*)d_in[30];
    const float* Wc2  = (const float*)d_in[31];
    const float* bc2  = (const float*)d_in[32];

    float* P  = (float*)d_ws;
    float* Q  = P + (size_t)NN * DH;
    float* R  = Q + (size_t)NN * DH;
    float* gf = R + (size_t)NN * DH;

    const int gemm_grid = (NN + 63) / 64;

    // ---- layer 1 (input dim 78) ----
    {
        int n2 = NN * DIN / 2;
        copy2_kernel<<<(n2 + 255) / 256, 256, 0, stream>>>((const float2*)x, (float2*)P, n2);
        unsigned total = (unsigned)NE * 39u;
        edge_agg78<<<(total + 255u) / 256u, 256, 0, stream>>>(x, src, dst, P);
        gemm_epi<DIN, 0><<<gemm_grid, 256, 0, stream>>>(P, c1W1, c1b1, nullptr, nullptr, Q, NN);
        gemm_epi<DH, 1><<<gemm_grid, 256, 0, stream>>>(Q, c1W2, c1b2, bn1g, bn1b, R, NN);
    }
    // ---- layer 2 ----
    {
        int n2 = NN * DH / 2;
        copy2_kernel<<<(n2 + 255) / 256, 256, 0, stream>>>((const float2*)R, (float2*)P, n2);
        unsigned total = (unsigned)NE * 32u;
        edge_agg128<<<(total + 255u) / 256u, 256, 0, stream>>>(R, src, dst, P);
        gemm_epi<DH, 0><<<gemm_grid, 256, 0, stream>>>(P, c2W1, c2b1, nullptr, nullptr, Q, NN);
        gemm_epi<DH, 1><<<gemm_grid, 256, 0, stream>>>(Q, c2W2, c2b2, bn2g, bn2b, R, NN);
    }
    // ---- layer 3 ----
    {
        int n2 = NN * DH / 2;
        copy2_kernel<<<(n2 + 255) / 256, 256, 0, stream>>>((const float2*)R, (float2*)P, n2);
        unsigned total = (unsigned)NE * 32u;
        edge_agg128<<<(total + 255u) / 256u, 256, 0, stream>>>(R, src, dst, P);
        gemm_epi<DH, 0><<<gemm_grid, 256, 0, stream>>>(P, c3W1, c3b1, nullptr, nullptr, Q, NN);
        gemm_epi<DH, 1><<<gemm_grid, 256, 0, stream>>>(Q, c3W2, c3b2, bn3g, bn3b, R, NN);
    }

    // ---- pool + fusion ----
    pool_kernel<<<NB, 1024, 0, stream>>>(R, batch, gf);
    fusion_kernel<<<NB, 256, 0, stream>>>(sem, gf, Ws, bs_, Wg, bg, Wq, Wk, Wv,
                                          Wc1, bc1, Wc2, bc2, (float*)d_out);
}

// Round 3
// 1269.776 us; speedup vs baseline: 5.6142x; 5.6142x over previous
//
#include <hip/hip_runtime.h>

#define NN 100000
#define NE 1600000
#define NB 64
#define DIN 78
#define DH 128
#define SD 768
#define FD 256
#define SCAN_NBLK 98   // ceil(NN/1024)

// 1/sqrt(1 + 1e-5)
#define BN_SCALE 0.9999950000374997f

// ================= CSR build =================
__global__ void zero_counts(int* __restrict__ counts) {
    int i = blockIdx.x * 1024 + threadIdx.x;
    if (i < NN) counts[i] = 0;
}

__global__ void hist_kernel(const int* __restrict__ dst, int* __restrict__ counts) {
    int e = blockIdx.x * 256 + threadIdx.x;
    if (e < NE) atomicAdd(&counts[dst[e]], 1);
}

// per-block exclusive scan (1024 elems/block) + block sums
__global__ __launch_bounds__(1024) void scan1(const int* __restrict__ counts,
                                              int* __restrict__ excl,
                                              int* __restrict__ bsums) {
    __shared__ int tmp[1024];
    int tid = threadIdx.x;
    int i = blockIdx.x * 1024 + tid;
    int v = (i < NN) ? counts[i] : 0;
    tmp[tid] = v;
    __syncthreads();
#pragma unroll
    for (int off = 1; off < 1024; off <<= 1) {
        int t = (tid >= off) ? tmp[tid - off] : 0;
        __syncthreads();
        tmp[tid] += t;
        __syncthreads();
    }
    if (i < NN) excl[i] = tmp[tid] - v;
    if (tid == 1023) bsums[blockIdx.x] = tmp[1023];
}

// exclusive scan of the block sums (single block, nb <= 128)
__global__ __launch_bounds__(128) void scan2(int* __restrict__ bsums, int nb) {
    __shared__ int tmp[128];
    int tid = threadIdx.x;
    int v = (tid < nb) ? bsums[tid] : 0;
    tmp[tid] = v;
    __syncthreads();
#pragma unroll
    for (int off = 1; off < 128; off <<= 1) {
        int t = (tid >= off) ? tmp[tid - off] : 0;
        __syncthreads();
        tmp[tid] += t;
        __syncthreads();
    }
    if (tid < nb) bsums[tid] = tmp[tid] - v;
}

__global__ void scan3(const int* __restrict__ excl, const int* __restrict__ bsums,
                      int* __restrict__ offsets, int* __restrict__ cursor) {
    int i = blockIdx.x * 1024 + threadIdx.x;
    if (i < NN) {
        int v = excl[i] + bsums[blockIdx.x];
        offsets[i] = v;
        cursor[i] = v;
    }
}

__global__ void scatter_kernel(const int* __restrict__ src, const int* __restrict__ dst,
                               int* __restrict__ cursor, int* __restrict__ eidx) {
    int e = blockIdx.x * 256 + threadIdx.x;
    if (e < NE) {
        int p = atomicAdd(&cursor[dst[e]], 1);
        eidx[p] = src[e];
    }
}

// ================= gather-based aggregation =================
// z[n] = h[n] + sum_{e: dst=n} h[src[e]]
// one 64-lane wave per node; lane covers a float2 of the feature row.
__global__ __launch_bounds__(256) void agg_csr128(const float* __restrict__ h,
                                                  const int* __restrict__ off,
                                                  const int* __restrict__ cnt,
                                                  const int* __restrict__ eidx,
                                                  float* __restrict__ z) {
    int node = blockIdx.x * 4 + (threadIdx.x >> 6);
    if (node >= NN) return;
    int lane = threadIdx.x & 63;
    int col = lane * 2;
    int start = off[node], deg = cnt[node];
    float2 sum = *(const float2*)&h[(size_t)node * DH + col];
    for (int base = 0; base < deg; base += 64) {
        int rem = deg - base;
        int m = rem < 64 ? rem : 64;
        int ev = (lane < m) ? eidx[start + base + lane] : 0;
#pragma unroll 4
        for (int j = 0; j < m; ++j) {
            int s = __shfl(ev, j);
            float2 v = *(const float2*)&h[(size_t)s * DH + col];
            sum.x += v.x;
            sum.y += v.y;
        }
    }
    *(float2*)&z[(size_t)node * DH + col] = sum;
}

// D=78 variant: lanes 0..38 hold float2 columns
__global__ __launch_bounds__(256) void agg_csr78(const float* __restrict__ h,
                                                 const int* __restrict__ off,
                                                 const int* __restrict__ cnt,
                                                 const int* __restrict__ eidx,
                                                 float* __restrict__ z) {
    int node = blockIdx.x * 4 + (threadIdx.x >> 6);
    if (node >= NN) return;
    int lane = threadIdx.x & 63;
    bool act = lane < 39;
    int col = lane * 2;
    int start = off[node], deg = cnt[node];
    float2 sum = make_float2(0.f, 0.f);
    if (act) sum = *(const float2*)&h[(size_t)node * DIN + col];
    for (int base = 0; base < deg; base += 64) {
        int rem = deg - base;
        int m = rem < 64 ? rem : 64;
        int ev = (lane < m) ? eidx[start + base + lane] : 0;
#pragma unroll 4
        for (int j = 0; j < m; ++j) {
            int s = __shfl(ev, j);
            if (act) {
                float2 v = *(const float2*)&h[(size_t)s * DIN + col];
                sum.x += v.x;
                sum.y += v.y;
            }
        }
    }
    if (act) *(float2*)&z[(size_t)node * DIN + col] = sum;
}

// ================= GEMM: C[N,128] = epi(A[N,K] @ W[K,128]) =================
// EPI 0: relu(acc + bias)
// EPI 1: relu((acc + bias) * (g*BN_SCALE) + bb)
template <int K, int EPI>
__global__ __launch_bounds__(256) void gemm_epi(
        const float* __restrict__ A, const float* __restrict__ W,
        const float* __restrict__ bias, const float* __restrict__ g,
        const float* __restrict__ bb, float* __restrict__ C, int nrows) {
    constexpr int BM = 64, BN = 128, BK = 64;
    __shared__ float As[BK][BM];   // transposed: As[k][row]
    __shared__ float Bs[BK][BN];
    const int tid = threadIdx.x;
    const int tx = tid & 15;       // col group (8 cols)
    const int ty = tid >> 4;       // row group (4 rows)
    const int r0 = blockIdx.x * BM;

    float acc[4][8];
#pragma unroll
    for (int i = 0; i < 4; ++i)
#pragma unroll
        for (int j = 0; j < 8; ++j) acc[i][j] = 0.f;

    const int tr = tid >> 2;       // 0..63 : A row within tile
    const int l4 = tid & 3;
    const int arow = r0 + tr;
    const bool aok = arow < nrows;

    for (int kt = 0; kt < K; kt += BK) {
        const int ksz = (K - kt < BK) ? (K - kt) : BK;
        for (int i = tid; i < ksz * (BN / 4); i += 256) {
            int kk = i >> 5;
            int cc = (i & 31) << 2;
            *(float4*)&Bs[kk][cc] = *(const float4*)&W[(size_t)(kt + kk) * BN + cc];
        }
        for (int k = l4; k < ksz; k += 4)
            As[k][tr] = aok ? A[(size_t)arow * K + kt + k] : 0.f;
        __syncthreads();

        if (ksz == BK) {
#pragma unroll
            for (int k = 0; k < BK; ++k) {
                float4 a4 = *(const float4*)&As[k][ty * 4];
                float4 b0 = *(const float4*)&Bs[k][tx * 8];
                float4 b1 = *(const float4*)&Bs[k][tx * 8 + 4];
                float av[4] = {a4.x, a4.y, a4.z, a4.w};
                float bv[8] = {b0.x, b0.y, b0.z, b0.w, b1.x, b1.y, b1.z, b1.w};
#pragma unroll
                for (int i = 0; i < 4; ++i)
#pragma unroll
                    for (int j = 0; j < 8; ++j)
                        acc[i][j] = fmaf(av[i], bv[j], acc[i][j]);
            }
        } else {
            for (int k = 0; k < ksz; ++k) {
                float4 a4 = *(const float4*)&As[k][ty * 4];
                float4 b0 = *(const float4*)&Bs[k][tx * 8];
                float4 b1 = *(const float4*)&Bs[k][tx * 8 + 4];
                float av[4] = {a4.x, a4.y, a4.z, a4.w};
                float bv[8] = {b0.x, b0.y, b0.z, b0.w, b1.x, b1.y, b1.z, b1.w};
#pragma unroll
                for (int i = 0; i < 4; ++i)
#pragma unroll
                    for (int j = 0; j < 8; ++j)
                        acc[i][j] = fmaf(av[i], bv[j], acc[i][j]);
            }
        }
        __syncthreads();
    }

#pragma unroll
    for (int i = 0; i < 4; ++i) {
        int row = r0 + ty * 4 + i;
        if (row >= nrows) continue;
        float out[8];
#pragma unroll
        for (int j = 0; j < 8; ++j) {
            int col = tx * 8 + j;
            float v = acc[i][j] + bias[col];
            if constexpr (EPI == 1) {
                v = v * (g[col] * BN_SCALE) + bb[col];
            }
            out[j] = fmaxf(v, 0.f);
        }
        *(float4*)&C[(size_t)row * BN + tx * 8] = *(float4*)&out[0];
        *(float4*)&C[(size_t)row * BN + tx * 8 + 4] = *(float4*)&out[4];
    }
}

// ================= global mean pool =================
__device__ __forceinline__ int lower_bound_i(const int* a, int n, int v) {
    int lo = 0, hi = n;
    while (lo < hi) {
        int m = (lo + hi) >> 1;
        if (a[m] < v) lo = m + 1; else hi = m;
    }
    return lo;
}

__global__ __launch_bounds__(1024) void pool_kernel(const float* __restrict__ h,
                                                    const int* __restrict__ batch,
                                                    float* __restrict__ gf) {
    int b = blockIdx.x;
    int f = threadIdx.x & 127;
    int chunk = threadIdx.x >> 7;   // 0..7
    __shared__ float part[8][DH];
    int lo = lower_bound_i(batch, NN, b);
    int hi = lower_bound_i(batch, NN, b + 1);
    float sum = 0.f;
    for (int i = lo + chunk; i < hi; i += 8) sum += h[(size_t)i * DH + f];
    part[chunk][f] = sum;
    __syncthreads();
    if (chunk == 0) {
        float s = part[0][f] + part[1][f] + part[2][f] + part[3][f] +
                  part[4][f] + part[5][f] + part[6][f] + part[7][f];
        int cnt = hi - lo;
        gf[b * DH + f] = s / (float)(cnt > 0 ? cnt : 1);
    }
}

// ================= fusion + attention + classifier =================
__global__ __launch_bounds__(256) void fusion_kernel(
        const float* __restrict__ sem, const float* __restrict__ gf,
        const float* __restrict__ Ws, const float* __restrict__ bs,
        const float* __restrict__ Wg, const float* __restrict__ bg,
        const float* __restrict__ Wq, const float* __restrict__ Wk,
        const float* __restrict__ Wv,
        const float* __restrict__ Wc1, const float* __restrict__ bc1,
        const float* __restrict__ Wc2, const float* __restrict__ bc2,
        float* __restrict__ out) {
    int b = blockIdx.x;
    int c = threadIdx.x;  // 256
    __shared__ float tok[2][FD];
    __shared__ float qv[6][FD];
    __shared__ float att[4];
    __shared__ float fused[FD];
    __shared__ float c1[FD / 2];

    {
        float acc = bs[c];
        const float* sr = &sem[(size_t)b * SD];
#pragma unroll 8
        for (int k = 0; k < SD; ++k) acc = fmaf(sr[k], Ws[(size_t)k * FD + c], acc);
        tok[0][c] = acc;
    }
    {
        float acc = bg[c];
        const float* gr = &gf[(size_t)b * DH];
#pragma unroll 8
        for (int k = 0; k < DH; ++k) acc = fmaf(gr[k], Wg[(size_t)k * FD + c], acc);
        tok[1][c] = acc;
    }
    __syncthreads();

#pragma unroll
    for (int t = 0; t < 2; ++t) {
        float qa = 0.f, ka = 0.f, va = 0.f;
#pragma unroll 4
        for (int k = 0; k < FD; ++k) {
            float tv = tok[t][k];
            qa = fmaf(tv, Wq[(size_t)k * FD + c], qa);
            ka = fmaf(tv, Wk[(size_t)k * FD + c], ka);
            va = fmaf(tv, Wv[(size_t)k * FD + c], va);
        }
        qv[0 + t][c] = qa;
        qv[2 + t][c] = ka;
        qv[4 + t][c] = va;
    }
    __syncthreads();

    if (c < 4) {
        int qi = c >> 1, ki = c & 1;
        float s = 0.f;
        for (int k = 0; k < FD; ++k) s += qv[qi][k] * qv[2 + ki][k];
        att[c] = s * (1.0f / 16.0f);
    }
    __syncthreads();
    if (c < 2) {
        float a0 = att[c * 2], a1 = att[c * 2 + 1];
        float m = fmaxf(a0, a1);
        float e0 = __expf(a0 - m), e1 = __expf(a1 - m);
        float inv = 1.f / (e0 + e1);
        att[c * 2] = e0 * inv;
        att[c * 2 + 1] = e1 * inv;
    }
    __syncthreads();

    fused[c] = 0.5f * (att[0] * qv[4][c] + att[1] * qv[5][c] +
                       att[2] * qv[4][c] + att[3] * qv[5][c]);
    __syncthreads();

    if (c < FD / 2) {
        float acc = bc1[c];
#pragma unroll 4
        for (int k = 0; k < FD; ++k) acc = fmaf(fused[k], Wc1[(size_t)k * (FD / 2) + c], acc);
        c1[c] = fmaxf(acc, 0.f);
    }
    __syncthreads();

    if (c < 2) {
        float acc = bc2[c];
        for (int k = 0; k < FD / 2; ++k) acc = fmaf(c1[k], Wc2[(size_t)k * 2 + c], acc);
        out[b * 2 + c] = acc;
    }
}

// ================= launch =================
extern "C" void kernel_launch(void* const* d_in, const int* in_sizes, int n_in,
                              void* d_out, int out_size, void* d_ws, size_t ws_size,
                              hipStream_t stream) {
    const float* sem   = (const float*)d_in[0];
    const float* x     = (const float*)d_in[1];
    const int*   ei    = (const int*)d_in[2];
    const int*   batch = (const int*)d_in[3];
    const int* src = ei;
    const int* dst = ei + NE;

    const float* c1W1 = (const float*)d_in[4];
    const float* c1b1 = (const float*)d_in[5];
    const float* c1W2 = (const float*)d_in[6];
    const float* c1b2 = (const float*)d_in[7];
    const float* c2W1 = (const float*)d_in[8];
    const float* c2b1 = (const float*)d_in[9];
    const float* c2W2 = (const float*)d_in[10];
    const float* c2b2 = (const float*)d_in[11];
    const float* c3W1 = (const float*)d_in[12];
    const float* c3b1 = (const float*)d_in[13];
    const float* c3W2 = (const float*)d_in[14];
    const float* c3b2 = (const float*)d_in[15];
    const float* bn1g = (const float*)d_in[16];
    const float* bn1b = (const float*)d_in[17];
    const float* bn2g = (const float*)d_in[18];
    const float* bn2b = (const float*)d_in[19];
    const float* bn3g = (const float*)d_in[20];
    const float* bn3b = (const float*)d_in[21];
    const float* Ws   = (const float*)d_in[22];
    const float* bs_  = (const float*)d_in[23];
    const float* Wg   = (const float*)d_in[24];
    const float* bg   = (const float*)d_in[25];
    const float* Wq   = (const float*)d_in[26];
    const float* Wk   = (const float*)d_in[27];
    const float* Wv   = (const float*)d_in[28];
    const float* Wc1  = (const float*)d_in[29];
    const float* bc1  = (const float*)d_in[30];
    const float* Wc2  = (const float*)d_in[31];
    const float* bc2  = (const float*)d_in[32];

    // workspace layout
    float* P  = (float*)d_ws;
    float* Q  = P + (size_t)NN * DH;
    float* R  = Q + (size_t)NN * DH;
    float* gf = R + (size_t)NN * DH;
    int* counts  = (int*)(gf + (size_t)NB * DH);
    int* offsets = counts + NN;
    int* cursor  = offsets + NN;
    int* excl    = cursor + NN;
    int* bsums   = excl + NN;
    int* eidx    = bsums + 128;

    const int gemm_grid = (NN + 63) / 64;
    const int agg_grid  = (NN + 3) / 4;
    const int edge_grid = (NE + 255) / 256;

    // ---- CSR build (once per call, reused by all 3 layers) ----
    zero_counts<<<SCAN_NBLK, 1024, 0, stream>>>(counts);
    hist_kernel<<<edge_grid, 256, 0, stream>>>(dst, counts);
    scan1<<<SCAN_NBLK, 1024, 0, stream>>>(counts, excl, bsums);
    scan2<<<1, 128, 0, stream>>>(bsums, SCAN_NBLK);
    scan3<<<SCAN_NBLK, 1024, 0, stream>>>(excl, bsums, offsets, cursor);
    scatter_kernel<<<edge_grid, 256, 0, stream>>>(src, dst, cursor, eidx);

    // ---- layer 1 (input dim 78) ----
    agg_csr78<<<agg_grid, 256, 0, stream>>>(x, offsets, counts, eidx, P);
    gemm_epi<DIN, 0><<<gemm_grid, 256, 0, stream>>>(P, c1W1, c1b1, nullptr, nullptr, Q, NN);
    gemm_epi<DH, 1><<<gemm_grid, 256, 0, stream>>>(Q, c1W2, c1b2, bn1g, bn1b, R, NN);

    // ---- layer 2 ----
    agg_csr128<<<agg_grid, 256, 0, stream>>>(R, offsets, counts, eidx, P);
    gemm_epi<DH, 0><<<gemm_grid, 256, 0, stream>>>(P, c2W1, c2b1, nullptr, nullptr, Q, NN);
    gemm_epi<DH, 1><<<gemm_grid, 256, 0, stream>>>(Q, c2W2, c2b2, bn2g, bn2b, R, NN);

    // ---- layer 3 ----
    agg_csr128<<<agg_grid, 256, 0, stream>>>(R, offsets, counts, eidx, P);
    gemm_epi<DH, 0><<<gemm_grid, 256, 0, stream>>>(P, c3W1, c3b1, nullptr, nullptr, Q, NN);
    gemm_epi<DH, 1><<<gemm_grid, 256, 0, stream>>>(Q, c3W2, c3b2, bn3g, bn3b, R, NN);

    // ---- pool + fusion ----
    pool_kernel<<<NB, 1024, 0, stream>>>(R, batch, gf);
    fusion_kernel<<<NB, 256, 0, stream>>>(sem, gf, Ws, bs_, Wg, bg, Wq, Wk, Wv,
                                          Wc1, bc1, Wc2, bc2, (float*)d_out);
}